// Round 2
// baseline (677.847 us; speedup 1.0000x reference)
//
#include <hip/hip_runtime.h>
#include <hip/hip_bf16.h>

#define TOKENS 8192
#define DMODEL 1024
#define NEXP   8
#define DFF    4096
#define CAP    1280

typedef short bf16x8_t __attribute__((ext_vector_type(8)));
typedef float f32x4_t  __attribute__((ext_vector_type(4)));

__device__ __forceinline__ float bf2f(ushort u) {
    union { unsigned int i; float f; } v; v.i = ((unsigned int)u) << 16; return v.f;
}
__device__ __forceinline__ ushort f2bf(float f) {
    union { float f; unsigned int i; } v; v.f = f;
    unsigned int r = v.i + 0x7fffu + ((v.i >> 16) & 1u);   // RNE
    return (ushort)(r >> 16);
}

// ---------------------------------------------------------------- gate ------
// One wave per token. fp32 logits, softmax, argmax (first-max tie-break).
__global__ __launch_bounds__(256) void gate_kernel(
    const float* __restrict__ tokens, const float* __restrict__ gw,
    int* __restrict__ eidx, float* __restrict__ prob)
{
    int lane = threadIdx.x & 63;
    int wave = threadIdx.x >> 6;
    int t = blockIdx.x * 4 + wave;
    const float* tok = tokens + (long)t * DMODEL;
    float s[NEXP] = {0.f,0.f,0.f,0.f,0.f,0.f,0.f,0.f};
    #pragma unroll
    for (int c = 0; c < 4; c++) {
        int d = c * 256 + lane * 4;
        float4 x = *(const float4*)(tok + d);
        #pragma unroll
        for (int e = 0; e < NEXP; e++) {
            float4 g = *(const float4*)(gw + e * DMODEL + d);
            s[e] += x.x*g.x + x.y*g.y + x.z*g.z + x.w*g.w;
        }
    }
    #pragma unroll
    for (int e = 0; e < NEXP; e++) {
        #pragma unroll
        for (int off = 32; off > 0; off >>= 1) s[e] += __shfl_xor(s[e], off);
    }
    if (lane == 0) {
        float m = s[0]; int am = 0;
        #pragma unroll
        for (int e = 1; e < NEXP; e++) if (s[e] > m) { m = s[e]; am = e; }
        float sum = 0.f;
        #pragma unroll
        for (int e = 0; e < NEXP; e++) sum += expf(s[e] - m);
        eidx[t] = am;
        prob[t] = 1.0f / sum;   // == softmax prob of argmax expert
    }
}

// ------------------------------------------------------------- routing ------
// Exact token-order rank per expert: single block, 256 threads x 32 tokens.
__global__ __launch_bounds__(256) void route_scan(
    const int* __restrict__ eidx, int* __restrict__ pos)
{
    __shared__ int hist[256][NEXP];
    int tid = threadIdx.x;
    int base = tid * 32;
    #pragma unroll
    for (int e = 0; e < NEXP; e++) hist[tid][e] = 0;
    for (int i = 0; i < 32; i++) hist[tid][eidx[base + i]]++;
    __syncthreads();
    if (tid < NEXP) {
        int run = 0;
        for (int i = 0; i < 256; i++) { int v = hist[i][tid]; hist[i][tid] = run; run += v; }
    }
    __syncthreads();
    for (int i = 0; i < 32; i++) {
        int e = eidx[base + i];
        pos[base + i] = hist[tid][e]++;
    }
}

// ------------------------------------------------------------ dispatch ------
// fp32 token -> bf16 dispatch row.
__global__ __launch_bounds__(256) void dispatch_gather(
    const float* __restrict__ tokens, const int* __restrict__ eidx,
    const int* __restrict__ pos, ushort* __restrict__ disp)
{
    int t = blockIdx.x;
    int p = pos[t];
    if (p >= CAP) return;
    int e = eidx[t];
    int d = threadIdx.x * 4;
    float4 v = *(const float4*)(tokens + (long)t * DMODEL + d);
    union { uint2 u; ushort h[4]; } o;
    o.h[0] = f2bf(v.x); o.h[1] = f2bf(v.y); o.h[2] = f2bf(v.z); o.h[3] = f2bf(v.w);
    *(uint2*)(disp + ((long)e * CAP + p) * DMODEL + d) = o.u;
}

// ----------------------------------------------------------- transpose ------
// out[c][r] = bf16(in[r][c]); fp32 in, bf16 out. 64x64 tiles, expert = blockIdx.z.
__global__ __launch_bounds__(256) void transpose_f32_bf16(
    const float* __restrict__ in, ushort* __restrict__ out, int R, int C)
{
    __shared__ ushort tile[64][72];
    long base = (long)blockIdx.z * R * C;
    int r0 = blockIdx.y * 64, c0 = blockIdx.x * 64;
    int tid = threadIdx.x;
    int rr = tid >> 2;
    int cc = (tid & 3) * 16;
    const float* ip = in + base + (long)(r0 + rr) * C + (c0 + cc);
    #pragma unroll
    for (int q = 0; q < 4; q++) {
        float4 v = *(const float4*)(ip + q * 4);
        tile[cc + q*4 + 0][rr] = f2bf(v.x);
        tile[cc + q*4 + 1][rr] = f2bf(v.y);
        tile[cc + q*4 + 2][rr] = f2bf(v.z);
        tile[cc + q*4 + 3][rr] = f2bf(v.w);
    }
    __syncthreads();
    ushort* op = out + base + (long)(c0 + rr) * R + (r0 + cc);
    *(uint4*)op       = *(const uint4*)&tile[rr][cc];
    *(uint4*)(op + 8) = *(const uint4*)&tile[rr][cc + 8];
}

// ---------------------------------------------------------------- GEMM ------
// C[M][N] = op(A[M][K] * B[N][K]^T + bias[N]); per-expert via blockIdx.z.
// 128x128 tile, BK=64, 4 waves, each wave 64x64 (4x4 of 16x16x32 MFMA).
__global__ __launch_bounds__(256) void gemm_bt(
    const ushort* __restrict__ A, const ushort* __restrict__ B,
    const float* __restrict__ bias, ushort* __restrict__ C,
    int M, int N, int K, int do_relu,
    long sA, long sB, long sBias, long sC)
{
    A += blockIdx.z * sA; B += blockIdx.z * sB;
    bias += blockIdx.z * sBias; C += blockIdx.z * sC;

    __shared__ ushort As[128][72];   // row stride 144B: 16B-aligned, balanced banks
    __shared__ ushort Bs[128][72];

    int tid  = threadIdx.x;
    int lane = tid & 63, wave = tid >> 6;
    int wm = (wave >> 1) * 64, wn = (wave & 1) * 64;
    int fm = lane & 15;             // fragment row/col within 16
    int fq = (lane >> 4) * 8;       // k-offset within 32-chunk
    int m0 = blockIdx.y * 128, n0 = blockIdx.x * 128;

    int sr = tid >> 3;              // 0..31
    int sc = (tid & 7) * 8;         // 0..56
    const ushort* Ag = A + (long)(m0 + sr) * K + sc;
    const ushort* Bg = B + (long)(n0 + sr) * K + sc;

    f32x4_t acc[4][4];
    #pragma unroll
    for (int i = 0; i < 4; i++)
        #pragma unroll
        for (int j = 0; j < 4; j++) acc[i][j] = (f32x4_t){0.f,0.f,0.f,0.f};

    for (int k0 = 0; k0 < K; k0 += 64) {
        #pragma unroll
        for (int i = 0; i < 4; i++) {
            *(uint4*)&As[sr + 32*i][sc] = *(const uint4*)(Ag + (long)(32*i) * K + k0);
            *(uint4*)&Bs[sr + 32*i][sc] = *(const uint4*)(Bg + (long)(32*i) * K + k0);
        }
        __syncthreads();
        #pragma unroll
        for (int kk = 0; kk < 64; kk += 32) {
            bf16x8_t af[4], bf[4];
            #pragma unroll
            for (int i = 0; i < 4; i++) af[i] = *(const bf16x8_t*)&As[wm + 16*i + fm][kk + fq];
            #pragma unroll
            for (int j = 0; j < 4; j++) bf[j] = *(const bf16x8_t*)&Bs[wn + 16*j + fm][kk + fq];
            #pragma unroll
            for (int i = 0; i < 4; i++)
                #pragma unroll
                for (int j = 0; j < 4; j++)
                    acc[i][j] = __builtin_amdgcn_mfma_f32_16x16x32_bf16(af[i], bf[j], acc[i][j], 0, 0, 0);
        }
        __syncthreads();
    }

    // epilogue: C/D layout col=lane&15, row=(lane>>4)*4+reg  [m89-verified]
    #pragma unroll
    for (int j = 0; j < 4; j++) {
        int col = n0 + wn + 16*j + fm;
        float bv = bias[col];
        #pragma unroll
        for (int i = 0; i < 4; i++) {
            int row = m0 + wm + 16*i + (lane >> 4) * 4;
            #pragma unroll
            for (int r = 0; r < 4; r++) {
                float v = acc[i][j][r] + bv;
                if (do_relu) v = fmaxf(v, 0.f);
                C[(long)(row + r) * N + col] = f2bf(v);
            }
        }
    }
}

// ------------------------------------------------------------- combine ------
// fp32 output: out[t] = prob[t] * eo[e][p]  (zeros for dropped tokens).
__global__ __launch_bounds__(256) void combine_kernel(
    const ushort* __restrict__ eo, const int* __restrict__ eidx,
    const int* __restrict__ pos, const float* __restrict__ prob,
    float* __restrict__ out)
{
    int t = blockIdx.x;
    int p = pos[t];
    int d = threadIdx.x * 4;
    float4 o;
    if (p < CAP) {
        int e = eidx[t];
        float w = prob[t];
        union { uint2 u; ushort h[4]; } v;
        v.u = *(const uint2*)(eo + ((long)e * CAP + p) * DMODEL + d);
        o.x = w * bf2f(v.h[0]);
        o.y = w * bf2f(v.h[1]);
        o.z = w * bf2f(v.h[2]);
        o.w = w * bf2f(v.h[3]);
    } else {
        o = (float4){0.f, 0.f, 0.f, 0.f};
    }
    *(float4*)(out + (long)t * DMODEL + d) = o;
}

// -------------------------------------------------------------- launch ------
extern "C" void kernel_launch(void* const* d_in, const int* in_sizes, int n_in,
                              void* d_out, int out_size, void* d_ws, size_t ws_size,
                              hipStream_t stream) {
    const float* tokens = (const float*)d_in[0];  // [8192][1024] fp32
    const float* gate_w = (const float*)d_in[1];  // [8][1024]
    const float* w1     = (const float*)d_in[2];  // [8][1024][4096]
    const float* b1     = (const float*)d_in[3];  // [8][4096]
    const float* w2     = (const float*)d_in[4];  // [8][4096][1024]
    const float* b2     = (const float*)d_in[5];  // [8][1024]
    float* outp = (float*)d_out;

    char* w = (char*)d_ws;
    ushort* w1T  = (ushort*)w; w += (size_t)NEXP * DFF * DMODEL * 2;   // 67 MB  bf16 [E][DFF][D]
    ushort* w2T  = (ushort*)w; w += (size_t)NEXP * DMODEL * DFF * 2;   // 67 MB  bf16 [E][D][DFF]
    ushort* disp = (ushort*)w; w += (size_t)NEXP * CAP * DMODEL * 2;   // 21 MB  bf16 [E][CAP][D]
    ushort* h    = (ushort*)w; w += (size_t)NEXP * CAP * DFF * 2;      // 84 MB  bf16 [E][CAP][DFF]
    ushort* eo   = (ushort*)w; w += (size_t)NEXP * CAP * DMODEL * 2;   // 21 MB  bf16 [E][CAP][D]
    int*   eidx  = (int*)w;   w += TOKENS * 4;
    int*   pos   = (int*)w;   w += TOKENS * 4;
    float* prob  = (float*)w; w += TOKENS * 4;

    // weight transposes + bf16 downcast: w1T[e][f][d] = w1[e][d][f], w2T[e][d][f] = w2[e][f][d]
    transpose_f32_bf16<<<dim3(DFF/64, DMODEL/64, NEXP), 256, 0, stream>>>(w1, w1T, DMODEL, DFF);
    transpose_f32_bf16<<<dim3(DMODEL/64, DFF/64, NEXP), 256, 0, stream>>>(w2, w2T, DFF, DMODEL);

    gate_kernel<<<TOKENS/4, 256, 0, stream>>>(tokens, gate_w, eidx, prob);
    route_scan<<<1, 256, 0, stream>>>(eidx, pos);
    dispatch_gather<<<TOKENS, 256, 0, stream>>>(tokens, eidx, pos, disp);

    // h = relu(disp @ w1 + b1)
    gemm_bt<<<dim3(DFF/128, CAP/128, NEXP), 256, 0, stream>>>(
        disp, w1T, b1, h, CAP, DFF, DMODEL, 1,
        (long)CAP*DMODEL, (long)DFF*DMODEL, DFF, (long)CAP*DFF);
    // eo = h @ w2 + b2
    gemm_bt<<<dim3(DMODEL/128, CAP/128, NEXP), 256, 0, stream>>>(
        h, w2T, b2, eo, CAP, DMODEL, DFF, 0,
        (long)CAP*DFF, (long)DMODEL*DFF, DMODEL, (long)CAP*DMODEL);

    combine_kernel<<<TOKENS, 256, 0, stream>>>(eo, eidx, pos, prob, outp);
}

// Round 3
// 581.766 us; speedup vs baseline: 1.1652x; 1.1652x over previous
//
#include <hip/hip_runtime.h>
#include <hip/hip_bf16.h>

#define TOKENS 8192
#define DMODEL 1024
#define NEXP   8
#define DFF    4096
#define CAP    1280

typedef short bf16x8_t __attribute__((ext_vector_type(8)));
typedef float f32x4_t  __attribute__((ext_vector_type(4)));

__device__ __forceinline__ float bf2f(ushort u) {
    union { unsigned int i; float f; } v; v.i = ((unsigned int)u) << 16; return v.f;
}
__device__ __forceinline__ ushort f2bf(float f) {
    union { float f; unsigned int i; } v; v.f = f;
    unsigned int r = v.i + 0x7fffu + ((v.i >> 16) & 1u);   // RNE
    return (ushort)(r >> 16);
}
// async global->LDS DMA, 16B per lane, dest = uniform base + lane*16
__device__ __forceinline__ void load_lds16(const void* g, void* l) {
    __builtin_amdgcn_global_load_lds(
        (const __attribute__((address_space(1))) void*)g,
        (__attribute__((address_space(3))) void*)l, 16, 0, 0);
}

// ---------------------------------------------------------------- gate ------
__global__ __launch_bounds__(256) void gate_kernel(
    const float* __restrict__ tokens, const float* __restrict__ gw,
    int* __restrict__ eidx, float* __restrict__ prob)
{
    int lane = threadIdx.x & 63;
    int wave = threadIdx.x >> 6;
    int t = blockIdx.x * 4 + wave;
    const float* tok = tokens + (long)t * DMODEL;
    float s[NEXP] = {0.f,0.f,0.f,0.f,0.f,0.f,0.f,0.f};
    #pragma unroll
    for (int c = 0; c < 4; c++) {
        int d = c * 256 + lane * 4;
        float4 x = *(const float4*)(tok + d);
        #pragma unroll
        for (int e = 0; e < NEXP; e++) {
            float4 g = *(const float4*)(gw + e * DMODEL + d);
            s[e] += x.x*g.x + x.y*g.y + x.z*g.z + x.w*g.w;
        }
    }
    #pragma unroll
    for (int e = 0; e < NEXP; e++) {
        #pragma unroll
        for (int off = 32; off > 0; off >>= 1) s[e] += __shfl_xor(s[e], off);
    }
    if (lane == 0) {
        float m = s[0]; int am = 0;
        #pragma unroll
        for (int e = 1; e < NEXP; e++) if (s[e] > m) { m = s[e]; am = e; }
        float sum = 0.f;
        #pragma unroll
        for (int e = 0; e < NEXP; e++) sum += expf(s[e] - m);
        eidx[t] = am;
        prob[t] = 1.0f / sum;
    }
}

// ------------------------------------------------------------- routing ------
__global__ __launch_bounds__(256) void route_scan(
    const int* __restrict__ eidx, int* __restrict__ pos)
{
    __shared__ int hist[256][NEXP];
    int tid = threadIdx.x;
    int base = tid * 32;
    #pragma unroll
    for (int e = 0; e < NEXP; e++) hist[tid][e] = 0;
    for (int i = 0; i < 32; i++) hist[tid][eidx[base + i]]++;
    __syncthreads();
    if (tid < NEXP) {
        int run = 0;
        for (int i = 0; i < 256; i++) { int v = hist[i][tid]; hist[i][tid] = run; run += v; }
    }
    __syncthreads();
    for (int i = 0; i < 32; i++) {
        int e = eidx[base + i];
        pos[base + i] = hist[tid][e]++;
    }
}

// ------------------------------------------------------------ dispatch ------
__global__ __launch_bounds__(256) void dispatch_gather(
    const float* __restrict__ tokens, const int* __restrict__ eidx,
    const int* __restrict__ pos, ushort* __restrict__ disp)
{
    int t = blockIdx.x;
    int p = pos[t];
    if (p >= CAP) return;
    int e = eidx[t];
    int d = threadIdx.x * 4;
    float4 v = *(const float4*)(tokens + (long)t * DMODEL + d);
    union { uint2 u; ushort h[4]; } o;
    o.h[0] = f2bf(v.x); o.h[1] = f2bf(v.y); o.h[2] = f2bf(v.z); o.h[3] = f2bf(v.w);
    *(uint2*)(disp + ((long)e * CAP + p) * DMODEL + d) = o.u;
}

// ----------------------------------------------------------- transpose ------
__global__ __launch_bounds__(256) void transpose_f32_bf16(
    const float* __restrict__ in, ushort* __restrict__ out, int R, int C)
{
    __shared__ ushort tile[64][72];
    long base = (long)blockIdx.z * R * C;
    int r0 = blockIdx.y * 64, c0 = blockIdx.x * 64;
    int tid = threadIdx.x;
    int rr = tid >> 2;
    int cc = (tid & 3) * 16;
    const float* ip = in + base + (long)(r0 + rr) * C + (c0 + cc);
    #pragma unroll
    for (int q = 0; q < 4; q++) {
        float4 v = *(const float4*)(ip + q * 4);
        tile[cc + q*4 + 0][rr] = f2bf(v.x);
        tile[cc + q*4 + 1][rr] = f2bf(v.y);
        tile[cc + q*4 + 2][rr] = f2bf(v.z);
        tile[cc + q*4 + 3][rr] = f2bf(v.w);
    }
    __syncthreads();
    ushort* op = out + base + (long)(c0 + rr) * R + (r0 + cc);
    *(uint4*)op       = *(const uint4*)&tile[rr][cc];
    *(uint4*)(op + 8) = *(const uint4*)&tile[rr][cc + 8];
}

// ---------------------------------------------------------------- GEMM ------
// C[M][N] = op(A[M][K] * B[N][K]^T + bias[N]); per-expert via blockIdx.z.
// 128x128 tile, BK=64, 4 waves. m97-style global_load_lds(16B) staging.
// LDS rows are 64 bf16 (128B = 8 chunks of 16B), XOR-swizzled: physical
// chunk p of row r holds logical chunk p ^ (r&7). Swizzle is applied on the
// GLOBAL address side so the DMA dest stays base + lane*16 (m104 constraint).
// Fragment ds_read_b128: 8 lanes per 16B bank-group = b128 conflict floor.
__global__ __launch_bounds__(256) void gemm_bt(
    const ushort* __restrict__ A, const ushort* __restrict__ B,
    const float* __restrict__ bias, ushort* __restrict__ C,
    int M, int N, int K, int do_relu,
    long sA, long sB, long sBias, long sC)
{
    A += blockIdx.z * sA; B += blockIdx.z * sB;
    bias += blockIdx.z * sBias; C += blockIdx.z * sC;

    __shared__ ushort As[128 * 64];   // 16 KB, unpadded (DMA layout)
    __shared__ ushort Bs[128 * 64];

    int tid  = threadIdx.x;
    int lane = tid & 63, wave = tid >> 6;
    int wm = (wave >> 1) * 64, wn = (wave & 1) * 64;
    int fm = lane & 15;             // fragment row/col within 16
    int q  = lane >> 4;             // 0..3  (k-quad)
    int rx = fm & 7;                // row&7 for swizzle on read side
    int m0 = blockIdx.y * 128, n0 = blockIdx.x * 128;

    // staging: lane i covers row (i>>3), swizzled chunk (i&7)^(i>>3)
    int srow = lane >> 3;                       // 0..7 within 8-row group
    int schk = (lane & 7) ^ srow;               // logical chunk to fetch
    const ushort* Ag = A + (long)(m0 + 32*wave + srow) * K + schk * 8;
    const ushort* Bg = B + (long)(n0 + 32*wave + srow) * K + schk * 8;
    ushort* AsW = &As[(32*wave) * 64];          // wave-uniform LDS bases
    ushort* BsW = &Bs[(32*wave) * 64];

    f32x4_t acc[4][4];
    #pragma unroll
    for (int i = 0; i < 4; i++)
        #pragma unroll
        for (int j = 0; j < 4; j++) acc[i][j] = (f32x4_t){0.f,0.f,0.f,0.f};

    for (int k0 = 0; k0 < K; k0 += 64) {
        #pragma unroll
        for (int t = 0; t < 4; t++) {
            load_lds16(Ag + (long)(8*t) * K + k0, AsW + (8*t) * 64);
            load_lds16(Bg + (long)(8*t) * K + k0, BsW + (8*t) * 64);
        }
        __syncthreads();   // compiler drains vmcnt before s_barrier
        #pragma unroll
        for (int kk = 0; kk < 64; kk += 32) {
            int l0 = (kk >> 3) + q;             // logical chunk for this frag
            bf16x8_t af[4], bf[4];
            #pragma unroll
            for (int i = 0; i < 4; i++) {
                int r = wm + 16*i + fm;
                af[i] = *(const bf16x8_t*)&As[r * 64 + (l0 ^ rx) * 8];
            }
            #pragma unroll
            for (int j = 0; j < 4; j++) {
                int r = wn + 16*j + fm;
                bf[j] = *(const bf16x8_t*)&Bs[r * 64 + (l0 ^ rx) * 8];
            }
            #pragma unroll
            for (int i = 0; i < 4; i++)
                #pragma unroll
                for (int j = 0; j < 4; j++)
                    acc[i][j] = __builtin_amdgcn_mfma_f32_16x16x32_bf16(af[i], bf[j], acc[i][j], 0, 0, 0);
        }
        __syncthreads();   // all reads done before next tile's DMA overwrites
    }

    // epilogue: C/D layout col=lane&15, row=(lane>>4)*4+reg  [m89-verified]
    #pragma unroll
    for (int j = 0; j < 4; j++) {
        int col = n0 + wn + 16*j + fm;
        float bv = bias[col];
        #pragma unroll
        for (int i = 0; i < 4; i++) {
            int row = m0 + wm + 16*i + q * 4;
            #pragma unroll
            for (int r = 0; r < 4; r++) {
                float v = acc[i][j][r] + bv;
                if (do_relu) v = fmaxf(v, 0.f);
                C[(long)(row + r) * N + col] = f2bf(v);
            }
        }
    }
}

// ------------------------------------------------------------- combine ------
__global__ __launch_bounds__(256) void combine_kernel(
    const ushort* __restrict__ eo, const int* __restrict__ eidx,
    const int* __restrict__ pos, const float* __restrict__ prob,
    float* __restrict__ out)
{
    int t = blockIdx.x;
    int p = pos[t];
    int d = threadIdx.x * 4;
    float4 o;
    if (p < CAP) {
        int e = eidx[t];
        float w = prob[t];
        union { uint2 u; ushort h[4]; } v;
        v.u = *(const uint2*)(eo + ((long)e * CAP + p) * DMODEL + d);
        o.x = w * bf2f(v.h[0]);
        o.y = w * bf2f(v.h[1]);
        o.z = w * bf2f(v.h[2]);
        o.w = w * bf2f(v.h[3]);
    } else {
        o = (float4){0.f, 0.f, 0.f, 0.f};
    }
    *(float4*)(out + (long)t * DMODEL + d) = o;
}

// -------------------------------------------------------------- launch ------
extern "C" void kernel_launch(void* const* d_in, const int* in_sizes, int n_in,
                              void* d_out, int out_size, void* d_ws, size_t ws_size,
                              hipStream_t stream) {
    const float* tokens = (const float*)d_in[0];  // [8192][1024] fp32
    const float* gate_w = (const float*)d_in[1];  // [8][1024]
    const float* w1     = (const float*)d_in[2];  // [8][1024][4096]
    const float* b1     = (const float*)d_in[3];  // [8][4096]
    const float* w2     = (const float*)d_in[4];  // [8][4096][1024]
    const float* b2     = (const float*)d_in[5];  // [8][1024]
    float* outp = (float*)d_out;

    char* w = (char*)d_ws;
    ushort* w1T  = (ushort*)w; w += (size_t)NEXP * DFF * DMODEL * 2;   // 67 MB  bf16 [E][DFF][D]
    ushort* w2T  = (ushort*)w; w += (size_t)NEXP * DMODEL * DFF * 2;   // 67 MB  bf16 [E][D][DFF]
    ushort* disp = (ushort*)w; w += (size_t)NEXP * CAP * DMODEL * 2;   // 21 MB  bf16 [E][CAP][D]
    ushort* h    = (ushort*)w; w += (size_t)NEXP * CAP * DFF * 2;      // 84 MB  bf16 [E][CAP][DFF]
    ushort* eo   = (ushort*)w; w += (size_t)NEXP * CAP * DMODEL * 2;   // 21 MB  bf16 [E][CAP][D]
    int*   eidx  = (int*)w;   w += TOKENS * 4;
    int*   pos   = (int*)w;   w += TOKENS * 4;
    float* prob  = (float*)w; w += TOKENS * 4;

    transpose_f32_bf16<<<dim3(DFF/64, DMODEL/64, NEXP), 256, 0, stream>>>(w1, w1T, DMODEL, DFF);
    transpose_f32_bf16<<<dim3(DMODEL/64, DFF/64, NEXP), 256, 0, stream>>>(w2, w2T, DFF, DMODEL);

    gate_kernel<<<TOKENS/4, 256, 0, stream>>>(tokens, gate_w, eidx, prob);
    route_scan<<<1, 256, 0, stream>>>(eidx, pos);
    dispatch_gather<<<TOKENS, 256, 0, stream>>>(tokens, eidx, pos, disp);

    // h = relu(disp @ w1 + b1)
    gemm_bt<<<dim3(DFF/128, CAP/128, NEXP), 256, 0, stream>>>(
        disp, w1T, b1, h, CAP, DFF, DMODEL, 1,
        (long)CAP*DMODEL, (long)DFF*DMODEL, DFF, (long)CAP*DFF);
    // eo = h @ w2 + b2
    gemm_bt<<<dim3(DMODEL/128, CAP/128, NEXP), 256, 0, stream>>>(
        h, w2T, b2, eo, CAP, DMODEL, DFF, 0,
        (long)CAP*DFF, (long)DMODEL*DFF, DMODEL, (long)CAP*DMODEL);

    combine_kernel<<<TOKENS, 256, 0, stream>>>(eo, eidx, pos, prob, outp);
}